// Round 13
// baseline (1003.678 us; speedup 1.0000x reference)
//
#include <hip/hip_runtime.h>

// Sizes (fixed by the problem)
#define NXc 256
#define NQc 256
#define NUc 128
#define Bc  8192
#define NHc 512
#define EPSc 0.001f

// ---------------------------------------------------------------------------
// Tiled f32 GEMM segment v2: accumulates a 64x64 C-tile over K.
// Block = 256 threads (16x16), 4x4 micro-tile, BK=32.
// ---------------------------------------------------------------------------
template<bool BT>
__device__ inline void gemm_seg(const float* __restrict__ A, int lda,
                                const float* __restrict__ Bm, int ldb,
                                int m0, int n0, int K,
                                float acc[4][4], float* As, float* Bs)
{
    const int tid = threadIdx.x;
    const int tx = tid & 15, ty = tid >> 4;
    const int ar  = tid >> 3;     // 0..31 (+32 on second pass)
    const int akc = tid & 7;      // float4 index along k
    for (int k0 = 0; k0 < K; k0 += 32) {
        __syncthreads();   // separates previous compute from new staging
        #pragma unroll
        for (int it = 0; it < 2; ++it) {
            const int r = ar + it * 32;
            const float4 a4 = *(const float4*)&A[(m0 + r) * lda + k0 + akc * 4];
            As[(akc * 4 + 0) * 68 + r] = a4.x;
            As[(akc * 4 + 1) * 68 + r] = a4.y;
            As[(akc * 4 + 2) * 68 + r] = a4.z;
            As[(akc * 4 + 3) * 68 + r] = a4.w;
        }
        if constexpr (BT) {
            #pragma unroll
            for (int it = 0; it < 2; ++it) {
                const int n = ar + it * 32;
                const float4 b4 = *(const float4*)&Bm[(n0 + n) * ldb + k0 + akc * 4];
                Bs[(akc * 4 + 0) * 68 + n] = b4.x;
                Bs[(akc * 4 + 1) * 68 + n] = b4.y;
                Bs[(akc * 4 + 2) * 68 + n] = b4.z;
                Bs[(akc * 4 + 3) * 68 + n] = b4.w;
            }
        } else {
            const int bn4 = tid & 15;   // n = bn4*4
            const int bk  = tid >> 4;   // 0..15 (+16 on second pass)
            #pragma unroll
            for (int it = 0; it < 2; ++it) {
                const int kk = bk + it * 16;
                *(float4*)&Bs[kk * 68 + bn4 * 4] =
                    *(const float4*)&Bm[(k0 + kk) * ldb + n0 + bn4 * 4];
            }
        }
        __syncthreads();
        #pragma unroll
        for (int kk = 0; kk < 32; ++kk) {
            const float4 a4 = *(const float4*)&As[kk * 68 + ty * 4];
            const float4 b4 = *(const float4*)&Bs[kk * 68 + tx * 4];
            const float av[4] = {a4.x, a4.y, a4.z, a4.w};
            const float bw[4] = {b4.x, b4.y, b4.z, b4.w};
            #pragma unroll
            for (int i = 0; i < 4; ++i)
                #pragma unroll
                for (int j = 0; j < 4; ++j)
                    acc[i][j] = __builtin_fmaf(av[i], bw[j], acc[i][j]);
        }
    }
}

// C = alpha * S @ S^T + EPS*I   (n x n, n multiple of 64)
__global__ __launch_bounds__(256) void k_gemm_sym(const float* __restrict__ S,
                                                  float* __restrict__ C,
                                                  int n, float alpha)
{
    __shared__ __align__(16) float As[32 * 68];
    __shared__ __align__(16) float Bs[32 * 68];
    float acc[4][4] = {};
    const int m0 = blockIdx.y * 64, n0 = blockIdx.x * 64;
    gemm_seg<true>(S, n, S, n, m0, n0, n, acc, As, Bs);
    const int tx = threadIdx.x & 15, ty = threadIdx.x >> 4;
    #pragma unroll
    for (int i = 0; i < 4; ++i)
        #pragma unroll
        for (int j = 0; j < 4; ++j) {
            int r = m0 + ty * 4 + i, c = n0 + tx * 4 + j;
            float v = alpha * acc[i][j];
            if (r == c) v += EPSc;
            C[r * n + c] = v;
        }
}

// From H (512x512), Chi, Y1: build YM = [Y | M] (256x512), D11T (256x256,
// TRANSPOSED: D11T[j][i] = D11[i][j]), linv (256).
__global__ void k_derive(const float* __restrict__ H, const float* __restrict__ Chi,
                         const float* __restrict__ Y1,
                         float* __restrict__ YM, float* __restrict__ D11T,
                         float* __restrict__ linv)
{
    const int i = blockIdx.x;
    const int j = threadIdx.x;
    const float li = 2.0f / H[(256 + i) * 512 + 256 + i];
    YM[i * 512 + j] = -0.5f * (H[i * 512 + j] + Y1[i * 256 + j] - Y1[j * 256 + i]);
    YM[i * 512 + 256 + j] = -H[i * 512 + 256 + j] - Chi[i * 256 + j];
    D11T[j * 256 + i] = (j < i) ? (-H[(256 + i) * 512 + 256 + j] * li) : 0.0f;
    if (j == 0) linv[i] = li;
}

// base = (xi @ Chi) * linv[col] + u @ D12^T + bv    -> basew (8192 x 256)
__global__ __launch_bounds__(256) void k_base(const float* __restrict__ xi,
                                              const float* __restrict__ u,
                                              const float* __restrict__ Chi,
                                              const float* __restrict__ D12,
                                              const float* __restrict__ bv,
                                              const float* __restrict__ linv,
                                              float* __restrict__ basew)
{
    __shared__ __align__(16) float As[32 * 68];
    __shared__ __align__(16) float Bs[32 * 68];
    float acc[4][4] = {};
    const int m0 = blockIdx.y * 64, n0 = blockIdx.x * 64;
    gemm_seg<false>(xi, 256, Chi, 256, m0, n0, 256, acc, As, Bs);
    const int tx = threadIdx.x & 15, ty = threadIdx.x >> 4;
    #pragma unroll
    for (int j = 0; j < 4; ++j) {
        float lv = linv[n0 + tx * 4 + j];
        #pragma unroll
        for (int i = 0; i < 4; ++i) acc[i][j] *= lv;
    }
    gemm_seg<true>(u, 128, D12, 128, m0, n0, 128, acc, As, Bs);
    #pragma unroll
    for (int i = 0; i < 4; ++i)
        #pragma unroll
        for (int j = 0; j < 4; ++j) {
            int r = m0 + ty * 4 + i, c = n0 + tx * 4 + j;
            basew[r * 256 + c] = acc[i][j] + bv[c];
        }
}

// ---------------------------------------------------------------------------
// Cholesky: P = L*L^T, lower triangle LDS-resident (packed, 131.6 KB).
// Body verbatim from R11 (validated). Own kernel so its LDS size doesn't
// poison other blocks (R11 lesson: static LDS is per-kernel, union-sized).
// ---------------------------------------------------------------------------
__global__ __launch_bounds__(1024) void k_chol(float* __restrict__ M)
{
    __shared__ __align__(16) float lt[32896];
    const int tid = threadIdx.x;
    for (int idx = tid; idx < 32896; idx += 1024) {
        int i = (int)((sqrtf(8.0f * (float)idx + 1.0f) - 1.0f) * 0.5f);
        while ((i + 1) * (i + 2) / 2 <= idx) ++i;
        while (i * (i + 1) / 2 > idx) --i;
        const int j = idx - i * (i + 1) / 2;
        lt[idx] = M[i * 256 + j];
    }
    __syncthreads();

    #pragma unroll 1
    for (int g = 0; g < 64; ++g) {
        const int k0 = 4 * g;
        const int o0 = (k0    ) * (k0 + 1) / 2 + k0;
        const int o1 = (k0 + 1) * (k0 + 2) / 2 + k0;
        const int o2 = (k0 + 2) * (k0 + 3) / 2 + k0;
        const int o3 = (k0 + 3) * (k0 + 4) / 2 + k0;
        float d00 = lt[o0];
        float d10 = lt[o1], d11v = lt[o1 + 1];
        float d20 = lt[o2], d21 = lt[o2 + 1], d22 = lt[o2 + 2];
        float d30 = lt[o3], d31 = lt[o3 + 1], d32 = lt[o3 + 2], d33 = lt[o3 + 3];
        d00 = sqrtf(d00);                 const float i00 = 1.0f / d00;
        d10 *= i00; d20 *= i00; d30 *= i00;
        d11v = sqrtf(d11v - d10 * d10);   const float i11 = 1.0f / d11v;
        d21 = (d21 - d20 * d10) * i11;
        d31 = (d31 - d30 * d10) * i11;
        d22 = sqrtf(d22 - d20 * d20 - d21 * d21); const float i22 = 1.0f / d22;
        d32 = (d32 - d30 * d20 - d31 * d21) * i22;
        d33 = sqrtf(d33 - d30 * d30 - d31 * d31 - d32 * d32);
        const float i33 = 1.0f / d33;
        for (int i = k0 + 4 + tid; i < 256; i += 1024) {
            const int o = i * (i + 1) / 2 + k0;
            float a0 = lt[o], a1 = lt[o + 1], a2 = lt[o + 2], a3 = lt[o + 3];
            a0 *= i00;
            a1 = (a1 - a0 * d10) * i11;
            a2 = (a2 - a0 * d20 - a1 * d21) * i22;
            a3 = (a3 - a0 * d30 - a1 * d31 - a2 * d32) * i33;
            lt[o] = a0; lt[o + 1] = a1; lt[o + 2] = a2; lt[o + 3] = a3;
        }
        __syncthreads();
        if (tid == 0) {
            lt[o0] = d00;
            lt[o1] = d10; lt[o1 + 1] = d11v;
            lt[o2] = d20; lt[o2 + 1] = d21; lt[o2 + 2] = d22;
            lt[o3] = d30; lt[o3 + 1] = d31; lt[o3 + 2] = d32; lt[o3 + 3] = d33;
        }
        for (int j = k0 + 4 + tid; j < 256; j += 1024) {
            const int oj = j * (j + 1) / 2 + k0;
            const float p0 = lt[oj], p1 = lt[oj + 1], p2 = lt[oj + 2], p3 = lt[oj + 3];
            int oi = oj;
            for (int i = j; i < 256; ++i) {
                const float q0 = lt[oi], q1 = lt[oi + 1];
                const float q2 = lt[oi + 2], q3 = lt[oi + 3];
                float v = lt[oi - k0 + j];
                v = __builtin_fmaf(-q0, p0, v);
                v = __builtin_fmaf(-q1, p1, v);
                v = __builtin_fmaf(-q2, p2, v);
                v = __builtin_fmaf(-q3, p3, v);
                lt[oi - k0 + j] = v;
                oi += i + 1;
            }
        }
        __syncthreads();
    }

    for (int idx = tid; idx < 32896; idx += 1024) {
        int i = (int)((sqrtf(8.0f * (float)idx + 1.0f) - 1.0f) * 0.5f);
        while ((i + 1) * (i + 2) / 2 <= idx) ++i;
        while (i * (i + 1) / 2 > idx) --i;
        const int j = idx - i * (i + 1) / 2;
        M[i * 256 + j] = lt[idx];
    }
}

// ---------------------------------------------------------------------------
// Scan v6 (1024 threads, 32 batch-rows/block, 32 lanes per row), D11T input:
//   w[:,i] = tanh(base[:,i] + sum_{j<i} w[:,j]*D11[i][j])
// Dense phase now COALESCED: lane t reads D11T[j][i0+t] (lanes consecutive,
// both wave halves identical -> broadcast); all 16 waves share the same
// ~28KB/c-block working set -> L1-resident (v4 read D11 row-per-lane:
// 32 scattered lines per load instruction, ~115K line-requests/block).
// Serial: dblkT[jj][t] staged coalesced from D11T; read jj*33+t conflict-free.
// ---------------------------------------------------------------------------
#define WPAD 264
__global__ __launch_bounds__(1024) void k_scan(const float* __restrict__ d11t,
                                               float* __restrict__ basew)
{
    __shared__ __align__(16) float wls[32 * WPAD];
    __shared__ __align__(16) float dblkT[32 * 33];
    const int tid = threadIdx.x;
    const int row0 = blockIdx.x * 32;
    for (int idx = tid; idx < 32 * 64; idx += 1024) {
        int r = idx >> 6, c4 = idx & 63;
        *(float4*)&wls[r * WPAD + c4 * 4] =
            *(const float4*)&basew[(row0 + r) * 256 + c4 * 4];
    }
    __syncthreads();

    const int r = tid >> 5;
    const int t = tid & 31;
    float* rowp = &wls[r * WPAD];
    const int sr = tid >> 3, sc4 = tid & 7;   // dblkT staging coords (tid<256)

    #pragma unroll 1
    for (int c = 0; c < 8; ++c) {
        const int i0 = 32 * c;
        if (tid < 256) {   // stage dblkT[jj][t] = D11T[i0+jj][i0+t], coalesced
            const float4 dv4 = *(const float4*)&d11t[(i0 + sr) * 256 + i0 + sc4 * 4];
            dblkT[sr * 33 + sc4 * 4 + 0] = dv4.x;
            dblkT[sr * 33 + sc4 * 4 + 1] = dv4.y;
            dblkT[sr * 33 + sc4 * 4 + 2] = dv4.z;
            dblkT[sr * 33 + sc4 * 4 + 3] = dv4.w;
        }
        // dense history: acc = base + sum_{j<i0} w[j] * D11T[j][i0+t]
        float acc = rowp[i0 + t];
        {
            const float* dcol = d11t + i0 + t;
            for (int j = 0; j < i0; j += 4) {
                const float4 w4 = *(const float4*)&rowp[j];
                const float dv0 = dcol[(j    ) * 256];
                const float dv1 = dcol[(j + 1) * 256];
                const float dv2 = dcol[(j + 2) * 256];
                const float dv3 = dcol[(j + 3) * 256];
                acc = __builtin_fmaf(w4.x, dv0, acc);
                acc = __builtin_fmaf(w4.y, dv1, acc);
                acc = __builtin_fmaf(w4.z, dv2, acc);
                acc = __builtin_fmaf(w4.w, dv3, acc);
            }
        }
        __syncthreads();              // dblkT staged
        #pragma unroll
        for (int jj = 0; jj < 32; ++jj) {
            const float v = 1.0f - 2.0f / (__expf(2.0f * acc) + 1.0f);
            const float wj = __shfl(v, jj, 32);   // broadcast from owner
            if (t == jj) rowp[i0 + jj] = v;       // off-chain store
            if (t > jj) acc = __builtin_fmaf(wj, dblkT[jj * 33 + t], acc);
        }
        __syncthreads();              // dblkT free for next c
    }

    for (int idx = tid; idx < 32 * 64; idx += 1024) {
        int rr = idx >> 6, c4 = idx & 63;
        *(float4*)&basew[(row0 + rr) * 256 + c4 * 4] =
            *(const float4*)&wls[rr * WPAD + c4 * 4];
    }
}

// ---------------------------------------------------------------------------
// Triangular solves: AB = P^{-1} YM via L L^T AB = YM. (verbatim R11)
// ---------------------------------------------------------------------------
__global__ __launch_bounds__(1024) void k_trs(const float* __restrict__ L,
                                              const float* __restrict__ YM,
                                              float* __restrict__ AB)
{
    __shared__ __align__(16) float pan[32 * WPAD];
    __shared__ float dblk[32 * 33];
    __shared__ float dinv[256];
    const int tid = threadIdx.x;
    const int col0 = blockIdx.x * 32;
    const int c = tid >> 5;
    const int t = tid & 31;
    float* colp = &pan[c * WPAD];

    for (int i = t; i < 256; i += 32)
        colp[i] = YM[i * 512 + col0 + c];
    if (tid < 256) dinv[tid] = 1.0f / L[tid * 256 + tid];
    __syncthreads();

    #pragma unroll 1
    for (int cb = 0; cb < 8; ++cb) {
        const int i0 = cb * 32;
        {
            const int rr = tid >> 5, qq = tid & 31;
            dblk[rr * 33 + qq] = (qq <= rr) ? L[(i0 + rr) * 256 + i0 + qq] : 0.0f;
        }
        float acc = colp[i0 + t];
        const float* lrow = L + (i0 + t) * 256;
        for (int j = 0; j < i0; j += 4) {
            const float4 z4 = *(const float4*)&colp[j];
            acc = __builtin_fmaf(-lrow[j    ], z4.x, acc);
            acc = __builtin_fmaf(-lrow[j + 1], z4.y, acc);
            acc = __builtin_fmaf(-lrow[j + 2], z4.z, acc);
            acc = __builtin_fmaf(-lrow[j + 3], z4.w, acc);
        }
        __syncthreads();
        #pragma unroll
        for (int jj = 0; jj < 32; ++jj) {
            const float v = acc * dinv[i0 + jj];
            const float wj = __shfl(v, jj, 32);
            if (t == jj) colp[i0 + jj] = v;
            if (t > jj) acc = __builtin_fmaf(-wj, dblk[t * 33 + jj], acc);
        }
        __syncthreads();
    }

    #pragma unroll 1
    for (int cb = 7; cb >= 0; --cb) {
        const int i0 = cb * 32;
        {
            const int rr = tid >> 5, qq = tid & 31;
            dblk[rr * 33 + qq] = (qq <= rr) ? L[(i0 + rr) * 256 + i0 + qq] : 0.0f;
        }
        float acc = colp[i0 + t];
        const int i = i0 + t;
        for (int j = i0 + 32; j < 256; j += 4) {
            const float4 x4 = *(const float4*)&colp[j];
            acc = __builtin_fmaf(-L[(j    ) * 256 + i], x4.x, acc);
            acc = __builtin_fmaf(-L[(j + 1) * 256 + i], x4.y, acc);
            acc = __builtin_fmaf(-L[(j + 2) * 256 + i], x4.z, acc);
            acc = __builtin_fmaf(-L[(j + 3) * 256 + i], x4.w, acc);
        }
        __syncthreads();
        #pragma unroll
        for (int jj = 31; jj >= 0; --jj) {
            const float v = acc * dinv[i0 + jj];
            const float wj = __shfl(v, jj, 32);
            if (t == jj) colp[i0 + jj] = v;
            if (t < jj) acc = __builtin_fmaf(-wj, dblk[jj * 33 + t], acc);
        }
        __syncthreads();
    }

    for (int i = t; i < 256; i += 32)
        AB[i * 512 + col0 + c] = colp[i];
}

// xi_dot = xi @ A^T + w @ B1^T + u @ B2^T + bx
__global__ __launch_bounds__(256) void k_final(const float* __restrict__ xi,
                                               const float* __restrict__ w,
                                               const float* __restrict__ u,
                                               const float* __restrict__ AB,
                                               const float* __restrict__ B2,
                                               const float* __restrict__ bx,
                                               float* __restrict__ out)
{
    __shared__ __align__(16) float As[32 * 68];
    __shared__ __align__(16) float Bs[32 * 68];
    float acc[4][4] = {};
    const int m0 = blockIdx.y * 64, n0 = blockIdx.x * 64;
    gemm_seg<true>(xi, 256, AB, 512, m0, n0, 256, acc, As, Bs);        // A-part
    gemm_seg<true>(w, 256, AB + 256, 512, m0, n0, 256, acc, As, Bs);   // B1-part
    gemm_seg<true>(u, 128, B2, 128, m0, n0, 128, acc, As, Bs);         // B2-part
    const int tx = threadIdx.x & 15, ty = threadIdx.x >> 4;
    #pragma unroll
    for (int i = 0; i < 4; ++i)
        #pragma unroll
        for (int j = 0; j < 4; ++j) {
            int r = m0 + ty * 4 + i, c = n0 + tx * 4 + j;
            out[r * 256 + c] = acc[i][j] + bx[c];
        }
}

extern "C" void kernel_launch(void* const* d_in, const int* in_sizes, int n_in,
                              void* d_out, int out_size, void* d_ws, size_t ws_size,
                              hipStream_t stream)
{
    (void)in_sizes; (void)n_in; (void)out_size; (void)ws_size;
    // setup_inputs order: t, xi, u, Pstar, Chi, Y1, B2, D12, X, bx, bv
    const float* xi    = (const float*)d_in[1];
    const float* u     = (const float*)d_in[2];
    const float* Pstar = (const float*)d_in[3];
    const float* Chi   = (const float*)d_in[4];
    const float* Y1    = (const float*)d_in[5];
    const float* B2    = (const float*)d_in[6];
    const float* D12   = (const float*)d_in[7];
    const float* X     = (const float*)d_in[8];
    const float* bx    = (const float*)d_in[9];
    const float* bv    = (const float*)d_in[10];
    float* out = (float*)d_out;

    float* ws    = (float*)d_ws;
    float* H     = ws;              // 512*512   = 262144
    float* YM    = H + 262144;      // 256*512   = 131072
    float* D11T  = YM + 131072;     // 256*256   =  65536  (transposed)
    float* linv  = D11T + 65536;    // 256
    float* Pm    = linv + 256;      // 256*256   =  65536  (becomes L)
    float* AB    = Pm + 65536;      // 256*512   = 131072
    float* basew = AB + 131072;     // 8192*256  = 2097152 (base, then w in-place)

    k_gemm_sym<<<dim3(8, 8), 256, 0, stream>>>(X, H, 512, 1.0f);         // H
    k_gemm_sym<<<dim3(4, 4), 256, 0, stream>>>(Pstar, Pm, 256, 0.5f);    // P
    k_derive  <<<dim3(256), 256, 0, stream>>>(H, Chi, Y1, YM, D11T, linv);
    k_base    <<<dim3(4, 128), 256, 0, stream>>>(xi, u, Chi, D12, bv, linv, basew);
    k_chol    <<<dim3(1), 1024, 0, stream>>>(Pm);                        // Pm -> L
    k_scan    <<<dim3(256), 1024, 0, stream>>>(D11T, basew);             // basew -> w
    k_trs     <<<dim3(16), 1024, 0, stream>>>(Pm, YM, AB);               // AB = P^-1 YM
    k_final   <<<dim3(4, 128), 256, 0, stream>>>(xi, basew, u, AB, B2, bx, out);
}

// Round 14
// 753.428 us; speedup vs baseline: 1.3321x; 1.3321x over previous
//
#include <hip/hip_runtime.h>

// Sizes (fixed by the problem)
#define NXc 256
#define NQc 256
#define NUc 128
#define Bc  8192
#define NHc 512
#define EPSc 0.001f

// ---------------------------------------------------------------------------
// Tiled f32 GEMM segment v2: accumulates a 64x64 C-tile over K.
// Block = 256 threads (16x16), 4x4 micro-tile, BK=32.
// ---------------------------------------------------------------------------
template<bool BT>
__device__ inline void gemm_seg(const float* __restrict__ A, int lda,
                                const float* __restrict__ Bm, int ldb,
                                int m0, int n0, int K,
                                float acc[4][4], float* As, float* Bs)
{
    const int tid = threadIdx.x;
    const int tx = tid & 15, ty = tid >> 4;
    const int ar  = tid >> 3;     // 0..31 (+32 on second pass)
    const int akc = tid & 7;      // float4 index along k
    for (int k0 = 0; k0 < K; k0 += 32) {
        __syncthreads();   // separates previous compute from new staging
        #pragma unroll
        for (int it = 0; it < 2; ++it) {
            const int r = ar + it * 32;
            const float4 a4 = *(const float4*)&A[(m0 + r) * lda + k0 + akc * 4];
            As[(akc * 4 + 0) * 68 + r] = a4.x;
            As[(akc * 4 + 1) * 68 + r] = a4.y;
            As[(akc * 4 + 2) * 68 + r] = a4.z;
            As[(akc * 4 + 3) * 68 + r] = a4.w;
        }
        if constexpr (BT) {
            #pragma unroll
            for (int it = 0; it < 2; ++it) {
                const int n = ar + it * 32;
                const float4 b4 = *(const float4*)&Bm[(n0 + n) * ldb + k0 + akc * 4];
                Bs[(akc * 4 + 0) * 68 + n] = b4.x;
                Bs[(akc * 4 + 1) * 68 + n] = b4.y;
                Bs[(akc * 4 + 2) * 68 + n] = b4.z;
                Bs[(akc * 4 + 3) * 68 + n] = b4.w;
            }
        } else {
            const int bn4 = tid & 15;   // n = bn4*4
            const int bk  = tid >> 4;   // 0..15 (+16 on second pass)
            #pragma unroll
            for (int it = 0; it < 2; ++it) {
                const int kk = bk + it * 16;
                *(float4*)&Bs[kk * 68 + bn4 * 4] =
                    *(const float4*)&Bm[(k0 + kk) * ldb + n0 + bn4 * 4];
            }
        }
        __syncthreads();
        #pragma unroll
        for (int kk = 0; kk < 32; ++kk) {
            const float4 a4 = *(const float4*)&As[kk * 68 + ty * 4];
            const float4 b4 = *(const float4*)&Bs[kk * 68 + tx * 4];
            const float av[4] = {a4.x, a4.y, a4.z, a4.w};
            const float bw[4] = {b4.x, b4.y, b4.z, b4.w};
            #pragma unroll
            for (int i = 0; i < 4; ++i)
                #pragma unroll
                for (int j = 0; j < 4; ++j)
                    acc[i][j] = __builtin_fmaf(av[i], bw[j], acc[i][j]);
        }
    }
}

// C = alpha * S @ S^T + EPS*I   (n x n, n multiple of 64)
__global__ __launch_bounds__(256) void k_gemm_sym(const float* __restrict__ S,
                                                  float* __restrict__ C,
                                                  int n, float alpha)
{
    __shared__ __align__(16) float As[32 * 68];
    __shared__ __align__(16) float Bs[32 * 68];
    float acc[4][4] = {};
    const int m0 = blockIdx.y * 64, n0 = blockIdx.x * 64;
    gemm_seg<true>(S, n, S, n, m0, n0, n, acc, As, Bs);
    const int tx = threadIdx.x & 15, ty = threadIdx.x >> 4;
    #pragma unroll
    for (int i = 0; i < 4; ++i)
        #pragma unroll
        for (int j = 0; j < 4; ++j) {
            int r = m0 + ty * 4 + i, c = n0 + tx * 4 + j;
            float v = alpha * acc[i][j];
            if (r == c) v += EPSc;
            C[r * n + c] = v;
        }
}

// From H (512x512), Chi, Y1: build YM = [Y | M] (256x512), D11T (256x256,
// TRANSPOSED: D11T[j][i] = D11[i][j]), linv (256).
__global__ void k_derive(const float* __restrict__ H, const float* __restrict__ Chi,
                         const float* __restrict__ Y1,
                         float* __restrict__ YM, float* __restrict__ D11T,
                         float* __restrict__ linv)
{
    const int i = blockIdx.x;
    const int j = threadIdx.x;
    const float li = 2.0f / H[(256 + i) * 512 + 256 + i];
    YM[i * 512 + j] = -0.5f * (H[i * 512 + j] + Y1[i * 256 + j] - Y1[j * 256 + i]);
    YM[i * 512 + 256 + j] = -H[i * 512 + 256 + j] - Chi[i * 256 + j];
    D11T[j * 256 + i] = (j < i) ? (-H[(256 + i) * 512 + 256 + j] * li) : 0.0f;
    if (j == 0) linv[i] = li;
}

// base = (xi @ Chi) * linv[col] + u @ D12^T + bv    -> basew (8192 x 256)
__global__ __launch_bounds__(256) void k_base(const float* __restrict__ xi,
                                              const float* __restrict__ u,
                                              const float* __restrict__ Chi,
                                              const float* __restrict__ D12,
                                              const float* __restrict__ bv,
                                              const float* __restrict__ linv,
                                              float* __restrict__ basew)
{
    __shared__ __align__(16) float As[32 * 68];
    __shared__ __align__(16) float Bs[32 * 68];
    float acc[4][4] = {};
    const int m0 = blockIdx.y * 64, n0 = blockIdx.x * 64;
    gemm_seg<false>(xi, 256, Chi, 256, m0, n0, 256, acc, As, Bs);
    const int tx = threadIdx.x & 15, ty = threadIdx.x >> 4;
    #pragma unroll
    for (int j = 0; j < 4; ++j) {
        float lv = linv[n0 + tx * 4 + j];
        #pragma unroll
        for (int i = 0; i < 4; ++i) acc[i][j] *= lv;
    }
    gemm_seg<true>(u, 128, D12, 128, m0, n0, 128, acc, As, Bs);
    #pragma unroll
    for (int i = 0; i < 4; ++i)
        #pragma unroll
        for (int j = 0; j < 4; ++j) {
            int r = m0 + ty * 4 + i, c = n0 + tx * 4 + j;
            basew[r * 256 + c] = acc[i][j] + bv[c];
        }
}

// ---------------------------------------------------------------------------
// Cholesky v2: rank-32 blocked, P = L*L^T (256x256 SPD). 8 rounds.
// lt: packed lower triangle, LDS-resident (131584 B).
// pb: panel buffer [224][36] (pad 36 -> float4-aligned rows, bank-spread);
//     pb[j*36+32] doubles as dinv[j] for the current diag block.
// Total LDS = 131584 + 32256 = 163840 B (exactly 160 KiB).
// Per round: (1) 32x32 diag factor on wave 0 (lane-per-row, shfl right-
// looking, fully unrolled); (2) panel solve = trs-forward pattern (32 lanes
// per row, 7 rows/team); (3) trailing rank-32 update with 2x2 register tiles
// reading the padded panel (reuse 32 vs old rank-4's 4 -> 8x less LDS traffic;
// old version: column-per-thread serial O(n) loop, 619us measured).
// ---------------------------------------------------------------------------
__global__ __launch_bounds__(1024) void k_chol(float* __restrict__ M)
{
    __shared__ __align__(16) float lt[32896];
    __shared__ __align__(16) float pb[224 * 36];
    const int tid = threadIdx.x;
    for (int idx = tid; idx < 32896; idx += 1024) {
        int i = (int)((sqrtf(8.0f * (float)idx + 1.0f) - 1.0f) * 0.5f);
        while ((i + 1) * (i + 2) / 2 <= idx) ++i;
        while (i * (i + 1) / 2 > idx) --i;
        lt[idx] = M[i * 256 + (idx - i * (i + 1) / 2)];
    }
    __syncthreads();

    #pragma unroll 1
    for (int r = 0; r < 8; ++r) {
        const int s = 32 * r;
        const int m = 224 - s;               // panel rows below diag block
        // ---- phase 1: diag block factor (wave 0, lane i = row i)
        if (tid < 32) {
            const int obase = (s + tid) * (s + tid + 1) / 2 + s;
            float d[32];
            #pragma unroll
            for (int j = 0; j < 32; ++j) d[j] = lt[obase + j];
            float mydiag = 1.0f;
            #pragma unroll
            for (int j = 0; j < 32; ++j) {
                const float dj = __shfl(d[j], j, 32);
                const float ljj = sqrtf(dj);
                const float inv = 1.0f / ljj;
                const float lij = (tid == j) ? ljj : d[j] * inv;
                if (tid == j) mydiag = ljj;
                if (tid >= j) lt[obase + j] = lij;
                #pragma unroll
                for (int k = 0; k < 32; ++k) if (k > j) {
                    const float lkj = __shfl(lij, k, 32);
                    d[k] = __builtin_fmaf(-lij, lkj, d[k]);
                }
            }
            pb[tid * 36 + 32] = 1.0f / mydiag;   // dinv in pad slot
        }
        __syncthreads();
        // ---- phase 2: panel solve (trs-forward pattern), 32 lanes/row
        {
            const int tm = tid >> 5, t = tid & 31;
            const int tbase = (s + t) * (s + t + 1) / 2 + s;  // Ld row t
            for (int i = s + 32 + tm; i < 256; i += 32) {
                const int oi = i * (i + 1) / 2 + s;
                float acc = lt[oi + t];
                float pv = 0.f;
                #pragma unroll
                for (int jj = 0; jj < 32; ++jj) {
                    const float v = __shfl(acc, jj, 32) * pb[jj * 36 + 32];
                    if (t == jj) pv = v;
                    if (t > jj) acc = __builtin_fmaf(-v, lt[tbase + jj], acc);
                }
                lt[oi + t] = pv;
                pb[(i - s - 32) * 36 + t] = pv;
            }
        }
        __syncthreads();
        // ---- phase 3: trailing rank-32 update, 2x2 register tiles
        {
            const int mb = m >> 1;                  // 2-row blocks
            const int nblk = mb * (mb + 1) / 2;
            for (int bidx = tid; bidx < nblk; bidx += 1024) {
                int a = (int)((sqrtf(8.0f * (float)bidx + 1.0f) - 1.0f) * 0.5f);
                while ((a + 1) * (a + 2) / 2 <= bidx) ++a;
                while (a * (a + 1) / 2 > bidx) --a;
                const int b = bidx - a * (a + 1) / 2;
                const float* pi0 = &pb[(2 * a) * 36];
                const float* pi1 = pi0 + 36;
                const float* pj0 = &pb[(2 * b) * 36];
                const float* pj1 = pj0 + 36;
                float a00 = 0.f, a01 = 0.f, a10 = 0.f, a11 = 0.f;
                #pragma unroll
                for (int p = 0; p < 32; p += 4) {
                    const float4 x0 = *(const float4*)&pi0[p];
                    const float4 x1 = *(const float4*)&pi1[p];
                    const float4 y0 = *(const float4*)&pj0[p];
                    const float4 y1 = *(const float4*)&pj1[p];
                    a00 = __builtin_fmaf(x0.x, y0.x, a00); a00 = __builtin_fmaf(x0.y, y0.y, a00);
                    a00 = __builtin_fmaf(x0.z, y0.z, a00); a00 = __builtin_fmaf(x0.w, y0.w, a00);
                    a01 = __builtin_fmaf(x0.x, y1.x, a01); a01 = __builtin_fmaf(x0.y, y1.y, a01);
                    a01 = __builtin_fmaf(x0.z, y1.z, a01); a01 = __builtin_fmaf(x0.w, y1.w, a01);
                    a10 = __builtin_fmaf(x1.x, y0.x, a10); a10 = __builtin_fmaf(x1.y, y0.y, a10);
                    a10 = __builtin_fmaf(x1.z, y0.z, a10); a10 = __builtin_fmaf(x1.w, y0.w, a10);
                    a11 = __builtin_fmaf(x1.x, y1.x, a11); a11 = __builtin_fmaf(x1.y, y1.y, a11);
                    a11 = __builtin_fmaf(x1.z, y1.z, a11); a11 = __builtin_fmaf(x1.w, y1.w, a11);
                }
                const int gi0 = s + 32 + 2 * a, gj0 = s + 32 + 2 * b;
                const int o0 = gi0 * (gi0 + 1) / 2;
                const int o1 = (gi0 + 1) * (gi0 + 2) / 2;
                lt[o0 + gj0] -= a00;
                if (a > b) lt[o0 + gj0 + 1] -= a01;   // skip above-diag elem
                lt[o1 + gj0] -= a10;
                lt[o1 + gj0 + 1] -= a11;
            }
        }
        __syncthreads();
    }

    for (int idx = tid; idx < 32896; idx += 1024) {
        int i = (int)((sqrtf(8.0f * (float)idx + 1.0f) - 1.0f) * 0.5f);
        while ((i + 1) * (i + 2) / 2 <= idx) ++i;
        while (i * (i + 1) / 2 > idx) --i;
        M[i * 256 + (idx - i * (i + 1) / 2)] = lt[idx];
    }
}

// ---------------------------------------------------------------------------
// Scan v6 (1024 threads, 32 batch-rows/block, 32 lanes per row), D11T input.
// ---------------------------------------------------------------------------
#define WPAD 264
__global__ __launch_bounds__(1024) void k_scan(const float* __restrict__ d11t,
                                               float* __restrict__ basew)
{
    __shared__ __align__(16) float wls[32 * WPAD];
    __shared__ __align__(16) float dblkT[32 * 33];
    const int tid = threadIdx.x;
    const int row0 = blockIdx.x * 32;
    for (int idx = tid; idx < 32 * 64; idx += 1024) {
        int r = idx >> 6, c4 = idx & 63;
        *(float4*)&wls[r * WPAD + c4 * 4] =
            *(const float4*)&basew[(row0 + r) * 256 + c4 * 4];
    }
    __syncthreads();

    const int r = tid >> 5;
    const int t = tid & 31;
    float* rowp = &wls[r * WPAD];
    const int sr = tid >> 3, sc4 = tid & 7;

    #pragma unroll 1
    for (int c = 0; c < 8; ++c) {
        const int i0 = 32 * c;
        if (tid < 256) {
            const float4 dv4 = *(const float4*)&d11t[(i0 + sr) * 256 + i0 + sc4 * 4];
            dblkT[sr * 33 + sc4 * 4 + 0] = dv4.x;
            dblkT[sr * 33 + sc4 * 4 + 1] = dv4.y;
            dblkT[sr * 33 + sc4 * 4 + 2] = dv4.z;
            dblkT[sr * 33 + sc4 * 4 + 3] = dv4.w;
        }
        float acc = rowp[i0 + t];
        {
            const float* dcol = d11t + i0 + t;
            for (int j = 0; j < i0; j += 4) {
                const float4 w4 = *(const float4*)&rowp[j];
                const float dv0 = dcol[(j    ) * 256];
                const float dv1 = dcol[(j + 1) * 256];
                const float dv2 = dcol[(j + 2) * 256];
                const float dv3 = dcol[(j + 3) * 256];
                acc = __builtin_fmaf(w4.x, dv0, acc);
                acc = __builtin_fmaf(w4.y, dv1, acc);
                acc = __builtin_fmaf(w4.z, dv2, acc);
                acc = __builtin_fmaf(w4.w, dv3, acc);
            }
        }
        __syncthreads();
        #pragma unroll
        for (int jj = 0; jj < 32; ++jj) {
            const float v = 1.0f - 2.0f / (__expf(2.0f * acc) + 1.0f);
            const float wj = __shfl(v, jj, 32);
            if (t == jj) rowp[i0 + jj] = v;
            if (t > jj) acc = __builtin_fmaf(wj, dblkT[jj * 33 + t], acc);
        }
        __syncthreads();
    }

    for (int idx = tid; idx < 32 * 64; idx += 1024) {
        int rr = idx >> 6, c4 = idx & 63;
        *(float4*)&basew[(row0 + rr) * 256 + c4 * 4] =
            *(const float4*)&wls[rr * WPAD + c4 * 4];
    }
}

// ---------------------------------------------------------------------------
// Triangular solves: AB = P^{-1} YM via L L^T AB = YM. (verbatim)
// ---------------------------------------------------------------------------
__global__ __launch_bounds__(1024) void k_trs(const float* __restrict__ L,
                                              const float* __restrict__ YM,
                                              float* __restrict__ AB)
{
    __shared__ __align__(16) float pan[32 * WPAD];
    __shared__ float dblk[32 * 33];
    __shared__ float dinv[256];
    const int tid = threadIdx.x;
    const int col0 = blockIdx.x * 32;
    const int c = tid >> 5;
    const int t = tid & 31;
    float* colp = &pan[c * WPAD];

    for (int i = t; i < 256; i += 32)
        colp[i] = YM[i * 512 + col0 + c];
    if (tid < 256) dinv[tid] = 1.0f / L[tid * 256 + tid];
    __syncthreads();

    #pragma unroll 1
    for (int cb = 0; cb < 8; ++cb) {
        const int i0 = cb * 32;
        {
            const int rr = tid >> 5, qq = tid & 31;
            dblk[rr * 33 + qq] = (qq <= rr) ? L[(i0 + rr) * 256 + i0 + qq] : 0.0f;
        }
        float acc = colp[i0 + t];
        const float* lrow = L + (i0 + t) * 256;
        for (int j = 0; j < i0; j += 4) {
            const float4 z4 = *(const float4*)&colp[j];
            acc = __builtin_fmaf(-lrow[j    ], z4.x, acc);
            acc = __builtin_fmaf(-lrow[j + 1], z4.y, acc);
            acc = __builtin_fmaf(-lrow[j + 2], z4.z, acc);
            acc = __builtin_fmaf(-lrow[j + 3], z4.w, acc);
        }
        __syncthreads();
        #pragma unroll
        for (int jj = 0; jj < 32; ++jj) {
            const float v = acc * dinv[i0 + jj];
            const float wj = __shfl(v, jj, 32);
            if (t == jj) colp[i0 + jj] = v;
            if (t > jj) acc = __builtin_fmaf(-wj, dblk[t * 33 + jj], acc);
        }
        __syncthreads();
    }

    #pragma unroll 1
    for (int cb = 7; cb >= 0; --cb) {
        const int i0 = cb * 32;
        {
            const int rr = tid >> 5, qq = tid & 31;
            dblk[rr * 33 + qq] = (qq <= rr) ? L[(i0 + rr) * 256 + i0 + qq] : 0.0f;
        }
        float acc = colp[i0 + t];
        const int i = i0 + t;
        for (int j = i0 + 32; j < 256; j += 4) {
            const float4 x4 = *(const float4*)&colp[j];
            acc = __builtin_fmaf(-L[(j    ) * 256 + i], x4.x, acc);
            acc = __builtin_fmaf(-L[(j + 1) * 256 + i], x4.y, acc);
            acc = __builtin_fmaf(-L[(j + 2) * 256 + i], x4.z, acc);
            acc = __builtin_fmaf(-L[(j + 3) * 256 + i], x4.w, acc);
        }
        __syncthreads();
        #pragma unroll
        for (int jj = 31; jj >= 0; --jj) {
            const float v = acc * dinv[i0 + jj];
            const float wj = __shfl(v, jj, 32);
            if (t == jj) colp[i0 + jj] = v;
            if (t < jj) acc = __builtin_fmaf(-wj, dblk[jj * 33 + t], acc);
        }
        __syncthreads();
    }

    for (int i = t; i < 256; i += 32)
        AB[i * 512 + col0 + c] = colp[i];
}

// xi_dot = xi @ A^T + w @ B1^T + u @ B2^T + bx
__global__ __launch_bounds__(256) void k_final(const float* __restrict__ xi,
                                               const float* __restrict__ w,
                                               const float* __restrict__ u,
                                               const float* __restrict__ AB,
                                               const float* __restrict__ B2,
                                               const float* __restrict__ bx,
                                               float* __restrict__ out)
{
    __shared__ __align__(16) float As[32 * 68];
    __shared__ __align__(16) float Bs[32 * 68];
    float acc[4][4] = {};
    const int m0 = blockIdx.y * 64, n0 = blockIdx.x * 64;
    gemm_seg<true>(xi, 256, AB, 512, m0, n0, 256, acc, As, Bs);        // A-part
    gemm_seg<true>(w, 256, AB + 256, 512, m0, n0, 256, acc, As, Bs);   // B1-part
    gemm_seg<true>(u, 128, B2, 128, m0, n0, 128, acc, As, Bs);         // B2-part
    const int tx = threadIdx.x & 15, ty = threadIdx.x >> 4;
    #pragma unroll
    for (int i = 0; i < 4; ++i)
        #pragma unroll
        for (int j = 0; j < 4; ++j) {
            int r = m0 + ty * 4 + i, c = n0 + tx * 4 + j;
            out[r * 256 + c] = acc[i][j] + bx[c];
        }
}

extern "C" void kernel_launch(void* const* d_in, const int* in_sizes, int n_in,
                              void* d_out, int out_size, void* d_ws, size_t ws_size,
                              hipStream_t stream)
{
    (void)in_sizes; (void)n_in; (void)out_size; (void)ws_size;
    // setup_inputs order: t, xi, u, Pstar, Chi, Y1, B2, D12, X, bx, bv
    const float* xi    = (const float*)d_in[1];
    const float* u     = (const float*)d_in[2];
    const float* Pstar = (const float*)d_in[3];
    const float* Chi   = (const float*)d_in[4];
    const float* Y1    = (const float*)d_in[5];
    const float* B2    = (const float*)d_in[6];
    const float* D12   = (const float*)d_in[7];
    const float* X     = (const float*)d_in[8];
    const float* bx    = (const float*)d_in[9];
    const float* bv    = (const float*)d_in[10];
    float* out = (float*)d_out;

    float* ws    = (float*)d_ws;
    float* H     = ws;              // 512*512   = 262144
    float* YM    = H + 262144;      // 256*512   = 131072
    float* D11T  = YM + 131072;     // 256*256   =  65536  (transposed)
    float* linv  = D11T + 65536;    // 256
    float* Pm    = linv + 256;      // 256*256   =  65536  (becomes L)
    float* AB    = Pm + 65536;      // 256*512   = 131072
    float* basew = AB + 131072;     // 8192*256  = 2097152 (base, then w in-place)

    k_gemm_sym<<<dim3(8, 8), 256, 0, stream>>>(X, H, 512, 1.0f);         // H
    k_gemm_sym<<<dim3(4, 4), 256, 0, stream>>>(Pstar, Pm, 256, 0.5f);    // P
    k_derive  <<<dim3(256), 256, 0, stream>>>(H, Chi, Y1, YM, D11T, linv);
    k_base    <<<dim3(4, 128), 256, 0, stream>>>(xi, u, Chi, D12, bv, linv, basew);
    k_chol    <<<dim3(1), 1024, 0, stream>>>(Pm);                        // Pm -> L
    k_scan    <<<dim3(256), 1024, 0, stream>>>(D11T, basew);             // basew -> w
    k_trs     <<<dim3(16), 1024, 0, stream>>>(Pm, YM, AB);               // AB = P^-1 YM
    k_final   <<<dim3(4, 128), 256, 0, stream>>>(xi, basew, u, AB, B2, bx, out);
}